// Round 2
// baseline (22.426 us; speedup 1.0000x reference)
//
#include <hip/hip_runtime.h>

#define KS   7
#define KK   49
#define MIDJ 24
#define H    256
#define W    320
#define HW   (H * W)
#define BS   4
#define ITERS 6

// Padded input geometry: 3 halo rows top/bottom, left pad 4 (so interior is
// 8B-aligned-friendly), right pad 1. All pad cells are zero.
#define PH   (H + 6)      // 262
#define PW   328          // row stride (W + 8)
#define XOFF 4            // x maps to column x+4
#define PAD_ELEMS (BS * PH * PW)   // 343744

// ---------------------------------------------------------------------------
// Pre-kernel: build zero-padded copy of `input` in workspace.
__global__ __launch_bounds__(256) void pad_kernel(
    const float* __restrict__ input,   // (BS, H, W)
    float*       __restrict__ pad)     // (BS, PH, PW)
{
    int idx = blockIdx.x * blockDim.x + threadIdx.x;
    if (idx >= PAD_ELEMS) return;
    int b  = idx / (PH * PW);
    int r  = idx - b * (PH * PW);
    int yp = r / PW;
    int xp = r - yp * PW;
    int y  = yp - 3;
    int x  = xp - XOFF;
    float v = 0.f;
    if (y >= 0 && y < H && x >= 0 && x < W)
        v = input[(size_t)b * HW + y * W + x];
    pad[idx] = v;
}

// ---------------------------------------------------------------------------
// Main fused kernel, 1 pixel per thread, all neighbor loads are
// immediate-offset loads off one base address (no per-tap VALU / branches).
__global__ __launch_bounds__(256) void dyspn_kernel(
    const float* __restrict__ kern,    // (BS, KK, HW)
    const float* __restrict__ pad,     // (BS, PH, PW) zero-padded input
    const float* __restrict__ input0,  // (BS, H, W)
    const float* __restrict__ att,     // (BS, ITERS, 4, HW)
    const int*   __restrict__ i_ptr,   // scalar
    float*       __restrict__ out)     // (BS, H, W)
{
    const int i_sel = *i_ptr;

    int idx = blockIdx.x * blockDim.x + threadIdx.x;
    if (idx >= BS * HW) return;

    int b = idx / HW;
    int p = idx - b * HW;
    int y = p / W;
    int x = p - y * W;

    // attention[b, i_sel, 0..3, p]
    const float* attb = att + ((size_t)(b * ITERS + i_sel)) * 4 * HW + p;
    float ar[4];
    ar[0] = attb[0];
    ar[1] = attb[HW];
    ar[2] = attb[2 * HW];
    ar[3] = attb[3 * HW];

    const float* kb   = kern + (size_t)b * KK * HW + p;
    const float* padb = pad + (size_t)b * PH * PW + (y + 3) * PW + (x + XOFF);
    const float  mid  = input0[(size_t)b * HW + p];

    float acc = 0.f, den = 0.f;

#pragma unroll
    for (int j = 0; j < KK; ++j) {
        const int dy = j / KS - 3;                    // compile-time
        const int dx = j % KS - 3;                    // compile-time
        const int r  = max(dy < 0 ? -dy : dy,
                           dx < 0 ? -dx : dx);        // ring id, compile-time

        float kv = kb[(size_t)j * HW];
        float v  = kv * ar[r];
        den += fabsf(v);

        float pv = (j == MIDJ) ? mid : padb[dy * PW + dx];  // imm-offset load
        acc = fmaf(v, pv, acc);
    }

    out[(size_t)b * HW + p] = acc / den;
}

// ---------------------------------------------------------------------------
// Fallback (no workspace): per-tap bounds-checked version (R0 kernel, 1px/t).
__global__ __launch_bounds__(256) void dyspn_kernel_checked(
    const float* __restrict__ kern,
    const float* __restrict__ input,
    const float* __restrict__ input0,
    const float* __restrict__ att,
    const int*   __restrict__ i_ptr,
    float*       __restrict__ out)
{
    const int i_sel = *i_ptr;
    int idx = blockIdx.x * blockDim.x + threadIdx.x;
    if (idx >= BS * HW) return;
    int b = idx / HW;
    int p = idx - b * HW;
    int y = p / W;
    int x = p - y * W;

    const float* attb = att + ((size_t)(b * ITERS + i_sel)) * 4 * HW + p;
    float ar[4] = {attb[0], attb[HW], attb[2 * HW], attb[3 * HW]};
    const float* kb  = kern + (size_t)b * KK * HW + p;
    const float* inb = input + (size_t)b * HW;
    const float  mid = input0[(size_t)b * HW + p];

    float acc = 0.f, den = 0.f;
#pragma unroll
    for (int j = 0; j < KK; ++j) {
        const int dy = j / KS - 3;
        const int dx = j % KS - 3;
        const int r  = max(dy < 0 ? -dy : dy, dx < 0 ? -dx : dx);
        float v = kb[(size_t)j * HW] * ar[r];
        den += fabsf(v);
        float pv;
        if (j == MIDJ) {
            pv = mid;
        } else {
            int yy = y + dy, xx = x + dx;
            pv = (yy >= 0 && yy < H && xx >= 0 && xx < W) ? inb[yy * W + xx] : 0.f;
        }
        acc = fmaf(v, pv, acc);
    }
    out[(size_t)b * HW + p] = acc / den;
}

extern "C" void kernel_launch(void* const* d_in, const int* in_sizes, int n_in,
                              void* d_out, int out_size, void* d_ws, size_t ws_size,
                              hipStream_t stream) {
    const float* kern   = (const float*)d_in[0];
    const float* input  = (const float*)d_in[1];
    const float* input0 = (const float*)d_in[2];
    const float* att    = (const float*)d_in[3];
    const int*   i_ptr  = (const int*)d_in[4];
    float* out = (float*)d_out;

    const int block = 256;
    const int grid_main = (BS * HW + block - 1) / block;   // 1280

    const size_t pad_bytes = (size_t)PAD_ELEMS * sizeof(float);
    if (ws_size >= pad_bytes) {
        float* pad = (float*)d_ws;
        const int grid_pad = (PAD_ELEMS + block - 1) / block;
        pad_kernel<<<grid_pad, block, 0, stream>>>(input, pad);
        dyspn_kernel<<<grid_main, block, 0, stream>>>(kern, pad, input0, att, i_ptr, out);
    } else {
        dyspn_kernel_checked<<<grid_main, block, 0, stream>>>(kern, input, input0, att, i_ptr, out);
    }
}